// Round 8
// baseline (914.244 us; speedup 1.0000x reference)
//
#include <hip/hip_runtime.h>
#include <hip/hip_bf16.h>

#define S_LEN 60
#define BATCH 256
#define EMB   300
#define EMBP  320              /* padded K for proj & x-part (zero cols 300..319) */
#define HID   512
#define DMLP  1024
#define NROW  (2*S_LEN*BATCH)  /* 30720 */
#define RPS   (S_LEN*BATCH)    /* 15360 */

typedef __attribute__((ext_vector_type(8))) short short8v;
typedef __attribute__((ext_vector_type(4))) float f32x4;

static __device__ __forceinline__ float sigf(float x){
  return 1.0f/(1.0f+__expf(-x));
}
static __device__ __forceinline__ float tanh_fast(float x){
  x = fminf(fmaxf(x,-40.0f),40.0f);
  float a = __expf(2.0f*x);
  return (a-1.0f)/(a+1.0f);
}
static __device__ __forceinline__ unsigned short f2b(float v){
  __hip_bfloat16 h = __float2bfloat16(v);
  return *(unsigned short*)&h;
}
static __device__ __forceinline__ float b2f(unsigned short u){
  return __uint_as_float(((unsigned int)u)<<16);
}

// ---------------------------------------------------------------------------
// K-conv: weights -> bf16 (Wih & projW padded), bsum = bih+bhh
// ---------------------------------------------------------------------------
__global__ __launch_bounds__(256) void k_conv_weights(
    const float* __restrict__ Wih, const float* __restrict__ Whh,
    const float* __restrict__ bih, const float* __restrict__ bhh,
    const float* __restrict__ projW,
    unsigned short* __restrict__ Wihb, unsigned short* __restrict__ Whhb,
    unsigned short* __restrict__ projWb, float* __restrict__ bsum)
{
  const int tid = blockIdx.x*256 + threadIdx.x;
  const int stride = gridDim.x*256;
  for (int i=tid; i<2048*EMBP; i+=stride){
    int n = i/EMBP, k = i - n*EMBP;
    Wihb[i] = f2b((k<EMB) ? Wih[(size_t)n*EMB + k] : 0.0f);
  }
  for (int i=tid; i<2048*HID; i+=stride) Whhb[i] = f2b(Whh[i]);
  for (int i=tid; i<EMBP*EMBP; i+=stride){
    int n = i/EMBP, k = i - n*EMBP;
    projWb[i] = f2b((n<EMB && k<EMB) ? projW[(size_t)n*EMB + k] : 0.0f);
  }
  for (int i=tid; i<2048; i+=stride) bsum[i] = bih[i]+bhh[i];
}

// ---------------------------------------------------------------------------
// K1: embedding gather + projection GEMM via MFMA -> bf16 P [30720][320]
// ---------------------------------------------------------------------------
__global__ __launch_bounds__(512) void k_embed_mfma(
    const float* __restrict__ embed, const unsigned short* __restrict__ projWb,
    const float* __restrict__ projb, const int* __restrict__ s1,
    const int* __restrict__ s2, unsigned short* __restrict__ Pb)
{
  __shared__ __align__(16) unsigned short sA0[64*40];
  __shared__ __align__(16) unsigned short sA1[64*40];
  __shared__ __align__(16) unsigned short sW0[64*40];
  __shared__ __align__(16) unsigned short sW1[64*40];
  __shared__ int stok[64];
  const int m0 = blockIdx.x*64, n0 = blockIdx.y*64;
  const int tid = threadIdx.x;
  if (tid < 64){
    int r = m0 + tid;
    stok[tid] = (r < RPS) ? s1[r] : s2[r-RPS];
  }
  __syncthreads();
  const int lane = tid & 63, w = tid>>6;
  const int wr = w>>2, wc = w&3;
  const bool isA = tid < 256;
  const int srow = (tid&255)>>2, sseg = tid&3;
  const float* Arow = embed + (size_t)stok[srow]*EMB;
  const unsigned short* Wrow = projWb + (size_t)(n0+srow)*EMBP;

  const int ldst = srow*40 + sseg*8;
  const int aoff0 = (wr*32 + (lane&15))*40 + (lane>>4)*8;
  const int aoff1 = aoff0 + 16*40;
  const int woff  = (wc*16 + (lane&15))*40 + (lane>>4)*8;

  f32x4 acc0 = {0.f,0.f,0.f,0.f}, acc1 = {0.f,0.f,0.f,0.f};

  auto loadA = [&](int kk)->uint4 {
    int kb = kk*32 + sseg*8;
    unsigned short t8[8];
    if (kb+7 < EMB){
      float4 f0 = *(const float4*)(Arow + kb);
      float4 f1 = *(const float4*)(Arow + kb + 4);
      t8[0]=f2b(f0.x); t8[1]=f2b(f0.y); t8[2]=f2b(f0.z); t8[3]=f2b(f0.w);
      t8[4]=f2b(f1.x); t8[5]=f2b(f1.y); t8[6]=f2b(f1.z); t8[7]=f2b(f1.w);
    } else {
      #pragma unroll
      for (int jq=0; jq<8; jq++){
        int k = kb+jq;
        t8[jq] = f2b((k<EMB) ? Arow[k] : 0.0f);
      }
    }
    uint4 o;
    o.x = (unsigned)t8[0] | ((unsigned)t8[1]<<16);
    o.y = (unsigned)t8[2] | ((unsigned)t8[3]<<16);
    o.z = (unsigned)t8[4] | ((unsigned)t8[5]<<16);
    o.w = (unsigned)t8[6] | ((unsigned)t8[7]<<16);
    return o;
  };

  if (isA) *(uint4*)(sA0 + ldst) = loadA(0);
  else     *(uint4*)(sW0 + ldst) = *(const uint4*)(Wrow + sseg*8);
  __syncthreads();

  for (int kk=0; kk<10; kk++){
    uint4 nv;
    if (kk < 9){
      if (isA) nv = loadA(kk+1);
      else     nv = *(const uint4*)(Wrow + (kk+1)*32 + sseg*8);
    }
    const unsigned short* A = (kk&1) ? sA1 : sA0;
    const unsigned short* W = (kk&1) ? sW1 : sW0;
    short8v af0 = *(const short8v*)(A + aoff0);
    short8v af1 = *(const short8v*)(A + aoff1);
    short8v wf  = *(const short8v*)(W + woff);
    acc0 = __builtin_amdgcn_mfma_f32_16x16x32_bf16(af0, wf, acc0, 0,0,0);
    acc1 = __builtin_amdgcn_mfma_f32_16x16x32_bf16(af1, wf, acc1, 0,0,0);
    if (kk < 9){
      unsigned short* dst = ((kk&1) ? (isA?sA0:sW0) : (isA?sA1:sW1)) + ldst;
      *(uint4*)dst = nv;
    }
    __syncthreads();
  }

  const int cc = wc*16 + (lane&15);
  const int n = n0 + cc;
  const float bias = (n < EMB) ? projb[n] : 0.0f;
  const bool valid = (n < EMB);
  #pragma unroll
  for (int v=0; v<4; v++){
    int r0 = wr*32 + (lane>>4)*4 + v;
    Pb[(size_t)(m0+r0)*EMBP + n]    = f2b(valid ? acc0[v]+bias : 0.0f);
    Pb[(size_t)(m0+r0+16)*EMBP + n] = f2b(valid ? acc1[v]+bias : 0.0f);
  }
}

// ---------------------------------------------------------------------------
// K2: BN partial sums over bf16 P
// ---------------------------------------------------------------------------
__global__ __launch_bounds__(320) void k_bn_partial(const unsigned short* __restrict__ Pb,
    float* __restrict__ ps, float* __restrict__ psq)
{
  const int rb = blockIdx.x, sent = blockIdx.y, t = threadIdx.x;
  if (t >= EMB) return;
  const unsigned short* base = Pb + ((size_t)sent*RPS + (size_t)rb*256)*EMBP;
  float s=0.0f, q=0.0f;
  for (int r=0;r<256;r++){
    float v = b2f(base[(size_t)r*EMBP + t]);
    s += v; q = fmaf(v,v,q);
  }
  ps [(size_t)(sent*60+rb)*EMB + t] = s;
  psq[(size_t)(sent*60+rb)*EMB + t] = q;
}

__global__ __launch_bounds__(320) void k_bn_final(const float* __restrict__ ps,
    const float* __restrict__ psq, const float* __restrict__ g,
    const float* __restrict__ b, float* __restrict__ scale, float* __restrict__ shift)
{
  const int sent = blockIdx.x, t = threadIdx.x;
  if (t >= EMB) return;
  float s=0.0f, q=0.0f;
  for (int i=0;i<60;i++){
    s += ps [(size_t)(sent*60+i)*EMB + t];
    q += psq[(size_t)(sent*60+i)*EMB + t];
  }
  float mean = s * (1.0f/15360.0f);
  float var  = q * (1.0f/15360.0f) - mean*mean;
  float sc = g[t] * rsqrtf(var + 1e-5f);
  scale[sent*EMB+t] = sc;
  shift[sent*EMB+t] = b[t] - mean*sc;
}

__global__ __launch_bounds__(256) void k_bn_apply(unsigned short* __restrict__ Pb,
    const float* __restrict__ scale, const float* __restrict__ shift)
{
  const int r = blockIdx.x*8 + (threadIdx.x>>5);
  const int c0 = threadIdx.x & 31;
  const int sent = (r >= RPS) ? 1 : 0;
  unsigned short* row = Pb + (size_t)r*EMBP;
  for (int c=c0; c<EMB; c+=32){
    float v = b2f(row[c]);
    v = fmaf(v, scale[sent*EMB+c], shift[sent*EMB+c]);
    row[c] = f2b(v);
  }
}

// ---------------------------------------------------------------------------
// K4: one LSTM step. Grid (32 j, 8 row), 512 thr. BK=128 (7 k-iters, was 13).
// Each thread stages 2 A-slots + 2 W-slots per chunk (subs s0, s0+2).
// LDS: A dbuf 2x10240ush + W dbuf 2x10240ush = 80KB; zs f32[64][66] overlays.
// ---------------------------------------------------------------------------
__global__ __launch_bounds__(512) void k_lstm_step(
    const unsigned short* __restrict__ Pb,    // [30720][320]
    const unsigned short* __restrict__ Wihb,  // [2048][320]
    const unsigned short* __restrict__ Whhb,  // [2048][512]
    const float* __restrict__ bsum,           // [2048]
    const unsigned short* __restrict__ Hin,   // [512][512]
    unsigned short* __restrict__ Hnext,       // [512][512]
    float* __restrict__ cst,                  // [512][512] f32
    unsigned short* __restrict__ Hout,        // [2][60][256][512]
    int tstep)
{
  __shared__ __align__(16) unsigned short smem[40960];   // 81920 B
  float* zs = (float*)smem;

  const int tid = threadIdx.x;
  const int lane = tid & 63, w = tid >> 6;
  const int wr = w >> 2, wc = w & 3;
  const int j0 = (int)blockIdx.x * 16;
  const int m0 = (int)blockIdx.y * 64;
  const int sent = m0 >> 8;
  const int brow = m0 & 255;

  // staging: thread owns (row,seg), sub-chunks s0 (slot0) and s0+2 (slot1)
  const int s0 = tid >> 8;            // 0..1
  const int rs = tid & 255;
  const int srow = rs >> 2, sseg = rs & 3;
  const int kb0 = s0*32 + sseg*8;     // col offset within 128-chunk, slot0
  const int kb1 = kb0 + 64;           // slot1 (subs 2,3)
  const int ld0 = s0*2560 + srow*40 + sseg*8;
  const int ld1 = ld0 + 5120;

  const unsigned short* ArowP = Pb + ((size_t)((sent*S_LEN + tstep)*BATCH) + brow + srow)*EMBP;
  const unsigned short* ArowH = Hin + (size_t)(m0 + srow)*HID;
  const int wn = (srow>>4)*HID + j0 + (srow&15);     // gate*512 + j
  const unsigned short* WrowX = Wihb + (size_t)wn*EMBP;
  const unsigned short* WrowH = Whhb + (size_t)wn*HID;

  auto loadAc = [&](int col)->uint4 {
    return (col < EMBP) ? *(const uint4*)(ArowP + col)
                        : *(const uint4*)(ArowH + col - EMBP);
  };
  auto loadWc = [&](int col)->uint4 {
    return (col < EMBP) ? *(const uint4*)(WrowX + col)
                        : *(const uint4*)(WrowH + col - EMBP);
  };

  const int aoffB = (wr*32 + (lane&15))*40 + (lane>>4)*8;
  const int woffB = (wc*16 + (lane&15))*40 + (lane>>4)*8;

  f32x4 acc0 = {0.f,0.f,0.f,0.f}, acc1 = {0.f,0.f,0.f,0.f};

  // prologue: stage chunk 0 -> buf0
  {
    uint4 a0 = loadAc(kb0), a1 = loadAc(kb1);
    uint4 w0 = loadWc(kb0), w1 = loadWc(kb1);
    *(uint4*)(smem + ld0) = a0;
    *(uint4*)(smem + ld1) = a1;
    *(uint4*)(smem + 20480 + ld0) = w0;
    *(uint4*)(smem + 20480 + ld1) = w1;
  }
  __syncthreads();

  // chunks: 0..5 full (128 cols), 6 partial (64 cols -> subs 0,1 only)
  #pragma unroll
  for (int kk = 0; kk < 7; kk++){
    uint4 pA0, pA1, pW0, pW1;
    if (kk < 6){
      int cbase = (kk+1)*128;
      pA0 = loadAc(cbase + kb0);
      pW0 = loadWc(cbase + kb0);
      if (kk+1 < 6){
        pA1 = loadAc(cbase + kb1);
        pW1 = loadWc(cbase + kb1);
      }
    }
    const unsigned short* A = smem + (kk&1)*10240;
    const unsigned short* W = smem + 20480 + (kk&1)*10240;
    #pragma unroll
    for (int s = 0; s < 4; s++){
      if (!(kk == 6 && s >= 2)){
        const int bh = s*2560;
        short8v wf  = *(const short8v*)(W + bh + woffB);
        short8v a0f = *(const short8v*)(A + bh + aoffB);
        short8v a1f = *(const short8v*)(A + bh + aoffB + 16*40);
        acc0 = __builtin_amdgcn_mfma_f32_16x16x32_bf16(a0f, wf, acc0, 0,0,0);
        acc1 = __builtin_amdgcn_mfma_f32_16x16x32_bf16(a1f, wf, acc1, 0,0,0);
      }
    }
    if (kk < 6){
      unsigned short* dA = smem + ((kk+1)&1)*10240;
      unsigned short* dW = smem + 20480 + ((kk+1)&1)*10240;
      *(uint4*)(dA + ld0) = pA0;
      *(uint4*)(dW + ld0) = pW0;
      if (kk+1 < 6){
        *(uint4*)(dA + ld1) = pA1;
        *(uint4*)(dW + ld1) = pW1;
      }
    }
    __syncthreads();
  }

  // epilogue: z -> LDS f32 [64][66] (overlays A buf, post-barrier)
  #pragma unroll
  for (int v = 0; v < 4; v++){
    int r0 = wr*32 + (lane>>4)*4 + v;
    int cc = wc*16 + (lane&15);
    zs[r0*66 + cc]      = acc0[v];
    zs[(r0+16)*66 + cc] = acc1[v];
  }
  __syncthreads();

  const int row_e = tid >> 4, jj = tid & 15, j = j0 + jj;
  const float zb0 = bsum[0*HID+j], zb1 = bsum[1*HID+j];
  const float zb2 = bsum[2*HID+j], zb3 = bsum[3*HID+j];
  #pragma unroll
  for (int q = 0; q < 2; q++){
    int row = row_e + q*32;
    int r = m0 + row;
    float zi = zs[row*66 + jj]    + zb0;
    float zf = zs[row*66 + 16+jj] + zb1;
    float zg = zs[row*66 + 32+jj] + zb2;
    float zo = zs[row*66 + 48+jj] + zb3;
    size_t ci = (size_t)r*HID + j;
    float cn = fmaf(sigf(zf), cst[ci], sigf(zi)*tanh_fast(zg));
    cst[ci] = cn;
    float hn = sigf(zo)*tanh_fast(cn);
    unsigned short hb = f2b(hn);
    Hnext[ci] = hb;
    Hout[((size_t)((sent*S_LEN + tstep)*BATCH) + (r&255))*HID + j] = hb;
  }
}

// ---------------------------------------------------------------------------
// K5: fused pairwise-L2-distance + 15x15 min-pool
// ---------------------------------------------------------------------------
#define SDU 258
__global__ __launch_bounds__(256) void k_dist_pool(
    const unsigned short* __restrict__ Hout, float* __restrict__ pooled)
{
  __shared__ unsigned int h1s[S_LEN*SDU];
  __shared__ unsigned int h2s[S_LEN*SDU];
  __shared__ float n1s[S_LEN], n2s[S_LEN];
  const int b = blockIdx.x, tid = threadIdx.x;
  const unsigned int* H = (const unsigned int*)Hout;
  for (int e=tid; e<S_LEN*256; e+=256){
    int row = e>>8, cu = e&255;
    h1s[row*SDU+cu] = H[((size_t)(0*S_LEN+row)*BATCH + b)*256 + cu];
    h2s[row*SDU+cu] = H[((size_t)(1*S_LEN+row)*BATCH + b)*256 + cu];
  }
  __syncthreads();
  if (tid < S_LEN){
    const unsigned int* rp = &h1s[tid*SDU];
    float q=0.0f;
    for (int cu=0;cu<256;cu++){
      unsigned int u = rp[cu];
      float lo = __uint_as_float(u<<16);
      float hi = __uint_as_float(u & 0xffff0000u);
      q = fmaf(lo,lo,q); q = fmaf(hi,hi,q);
    }
    n1s[tid] = q;
  } else if (tid >= 64 && tid < 64+S_LEN){
    const unsigned int* rp = &h2s[(tid-64)*SDU];
    float q=0.0f;
    for (int cu=0;cu<256;cu++){
      unsigned int u = rp[cu];
      float lo = __uint_as_float(u<<16);
      float hi = __uint_as_float(u & 0xffff0000u);
      q = fmaf(lo,lo,q); q = fmaf(hi,hi,q);
    }
    n2s[tid-64] = q;
  }
  __syncthreads();
  if (tid < 225){
    const int gi = tid/15, gj = tid%15;
    float acc[4][4];
    #pragma unroll
    for (int a=0;a<4;a++)
      #pragma unroll
      for (int c=0;c<4;c++) acc[a][c]=0.0f;
    const unsigned int* r1[4]; const unsigned int* r2[4];
    #pragma unroll
    for (int a=0;a<4;a++){ r1[a]=&h1s[(gi*4+a)*SDU]; r2[a]=&h2s[(gj*4+a)*SDU]; }
    for (int cu=0;cu<256;cu++){
      float lo1[4],hi1[4],lo2[4],hi2[4];
      #pragma unroll
      for (int a=0;a<4;a++){
        unsigned int u = r1[a][cu];
        lo1[a]=__uint_as_float(u<<16); hi1[a]=__uint_as_float(u&0xffff0000u);
      }
      #pragma unroll
      for (int c=0;c<4;c++){
        unsigned int u = r2[c][cu];
        lo2[c]=__uint_as_float(u<<16); hi2[c]=__uint_as_float(u&0xffff0000u);
      }
      #pragma unroll
      for (int a=0;a<4;a++)
        #pragma unroll
        for (int c=0;c<4;c++)
          acc[a][c] = fmaf(lo1[a],lo2[c], fmaf(hi1[a],hi2[c], acc[a][c]));
    }
    float mn = 3.4e38f;
    #pragma unroll
    for (int a=0;a<4;a++)
      #pragma unroll
      for (int c=0;c<4;c++){
        float sq = n1s[gi*4+a] + n2s[gj*4+c] - 2.0f*acc[a][c];
        mn = fminf(mn, sqrtf(fmaxf(sq,0.0f)+1e-12f));
      }
    pooled[(size_t)b*225 + tid] = mn;
  }
}

// ---------------------------------------------------------------------------
// MLP layer 1: fp32 tiled GEMM M=256,N=1024,K=232(pad 256). bias+relu fused.
// grid (16 n-tiles, 4 m-tiles), 256 thr, 64x64 tile, 4x4 microtile.
// ---------------------------------------------------------------------------
__global__ __launch_bounds__(256) void k_mlp1_gemm(
    const float* __restrict__ pooled, const float* __restrict__ extra,
    const float* __restrict__ W1, const float* __restrict__ b1,
    float* __restrict__ y1)
{
  __shared__ float As[64][33];
  __shared__ float Bs[64][33];
  const int n0 = blockIdx.x*64, m0 = blockIdx.y*64;
  const int tid = threadIdx.x;
  const int tx = tid & 15, ty = tid >> 4;
  float acc[4][4];
  #pragma unroll
  for (int a=0;a<4;a++)
    #pragma unroll
    for (int b=0;b<4;b++) acc[a][b]=0.0f;

  for (int k0=0; k0<256; k0+=32){
    #pragma unroll
    for (int i=0;i<8;i++){
      int e = tid + i*256;
      int rl = e>>5, kl = e&31;
      int c = k0 + kl;
      float av;
      if (c < 225)      av = pooled[(size_t)(m0+rl)*225 + c];
      else if (c < 232) av = extra[(size_t)(m0+rl)*7 + (c-225)];
      else              av = 0.0f;
      As[rl][kl] = av;
      Bs[rl][kl] = (c < 232) ? W1[(size_t)(n0+rl)*232 + c] : 0.0f;
    }
    __syncthreads();
    #pragma unroll
    for (int kk=0;kk<32;kk++){
      float a[4], wv[4];
      #pragma unroll
      for (int rl=0;rl<4;rl++) a[rl] = As[ty*4+rl][kk];
      #pragma unroll
      for (int cj=0;cj<4;cj++) wv[cj] = Bs[cj*16+tx][kk];
      #pragma unroll
      for (int rl=0;rl<4;rl++)
        #pragma unroll
        for (int cj=0;cj<4;cj++) acc[rl][cj] = fmaf(a[rl], wv[cj], acc[rl][cj]);
    }
    __syncthreads();
  }
  #pragma unroll
  for (int rl=0;rl<4;rl++){
    int r = m0 + ty*4 + rl;
    #pragma unroll
    for (int cj=0;cj<4;cj++){
      int n = n0 + cj*16 + tx;
      y1[(size_t)r*DMLP + n] = fmaxf(acc[rl][cj] + b1[n], 0.0f);
    }
  }
}

// BN stats over batch: 16 blocks x 256 thr; block owns 64 channels, 4 row-groups
__global__ __launch_bounds__(256) void k_mlp_bn2(const float* __restrict__ y,
    const float* __restrict__ g, const float* __restrict__ be,
    float* __restrict__ scale, float* __restrict__ shift)
{
  __shared__ float sred[256], qred[256];
  const int c0 = blockIdx.x*64;
  const int ch = threadIdx.x & 63, grp = threadIdx.x >> 6;
  const int n = c0 + ch;
  float s=0.0f, q=0.0f;
  for (int b=grp*64; b<grp*64+64; b++){
    float v = y[(size_t)b*DMLP + n];
    s += v; q = fmaf(v,v,q);
  }
  sred[threadIdx.x]=s; qred[threadIdx.x]=q;
  __syncthreads();
  if (grp==0){
    s = sred[ch] + sred[64+ch] + sred[128+ch] + sred[192+ch];
    q = qred[ch] + qred[64+ch] + qred[128+ch] + qred[192+ch];
    float mean = s * (1.0f/256.0f);
    float var  = q * (1.0f/256.0f) - mean*mean;
    float sc = g[n] * rsqrtf(var + 1e-5f);
    scale[n] = sc;
    shift[n] = be[n] - mean*sc;
  }
}

// MLP2 GEMM fp32, split-K x4: grid (16 nt, 4 mt, 4 kc), 256 thr, 64x64 tile
__global__ __launch_bounds__(256) void k_mlp2_gemm(
    const float* __restrict__ y1, const float* __restrict__ scale1,
    const float* __restrict__ shift1, const float* __restrict__ W2,
    float* __restrict__ y2part)
{
  __shared__ float As[64][33];
  __shared__ float Bs[64][33];
  const int n0 = blockIdx.x*64, m0 = blockIdx.y*64;
  const int kbase = blockIdx.z*256;
  const int tid = threadIdx.x;
  const int tx = tid & 15, ty = tid >> 4;
  float acc[4][4];
  #pragma unroll
  for (int a=0;a<4;a++)
    #pragma unroll
    for (int b=0;b<4;b++) acc[a][b]=0.0f;

  for (int k0=0; k0<256; k0+=32){
    #pragma unroll
    for (int i=0;i<8;i++){
      int e = tid + i*256;
      int rl = e>>5, kl = e&31;
      int kk = kbase + k0 + kl;
      As[rl][kl] = fmaf(y1[(size_t)(m0+rl)*DMLP + kk], scale1[kk], shift1[kk]);
      Bs[rl][kl] = W2[(size_t)(n0+rl)*DMLP + kk];
    }
    __syncthreads();
    #pragma unroll
    for (int kk=0;kk<32;kk++){
      float a[4], w[4];
      #pragma unroll
      for (int rl=0;rl<4;rl++) a[rl] = As[ty*4+rl][kk];
      #pragma unroll
      for (int cj=0;cj<4;cj++) w[cj] = Bs[cj*16+tx][kk];
      #pragma unroll
      for (int rl=0;rl<4;rl++)
        #pragma unroll
        for (int cj=0;cj<4;cj++) acc[rl][cj] = fmaf(a[rl], w[cj], acc[rl][cj]);
    }
    __syncthreads();
  }
  float* dst = y2part + ((size_t)blockIdx.z*BATCH)*DMLP;
  #pragma unroll
  for (int rl=0;rl<4;rl++){
    int r = m0 + ty*4 + rl;
    #pragma unroll
    for (int cj=0;cj<4;cj++){
      int n = n0 + cj*16 + tx;
      dst[(size_t)r*DMLP + n] = acc[rl][cj];
    }
  }
}

// finalize: y2 = relu(sum_k y2part + bias)
__global__ __launch_bounds__(256) void k_mlp2_fin(
    const float* __restrict__ y2part, const float* __restrict__ b2,
    float* __restrict__ y2)
{
  const int b = blockIdx.x;
  const int n = threadIdx.x*4;
  float4 p0 = *(const float4*)(y2part + ((size_t)(0*BATCH + b))*DMLP + n);
  float4 p1 = *(const float4*)(y2part + ((size_t)(1*BATCH + b))*DMLP + n);
  float4 p2 = *(const float4*)(y2part + ((size_t)(2*BATCH + b))*DMLP + n);
  float4 p3 = *(const float4*)(y2part + ((size_t)(3*BATCH + b))*DMLP + n);
  float4 bb = *(const float4*)(b2 + n);
  float4 o;
  o.x = fmaxf(p0.x+p1.x+p2.x+p3.x+bb.x, 0.0f);
  o.y = fmaxf(p0.y+p1.y+p2.y+p3.y+bb.y, 0.0f);
  o.z = fmaxf(p0.z+p1.z+p2.z+p3.z+bb.z, 0.0f);
  o.w = fmaxf(p0.w+p1.w+p2.w+p3.w+bb.w, 0.0f);
  *(float4*)(y2 + (size_t)b*DMLP + n) = o;
}

__global__ __launch_bounds__(256) void k_mlp3(const float* __restrict__ y2,
    const float* __restrict__ scale2, const float* __restrict__ shift2,
    const float* __restrict__ W3, const float* __restrict__ b3,
    float* __restrict__ out)
{
  __shared__ float r0[256], r1[256];
  const int b = blockIdx.x, tid = threadIdx.x;
  float p0=0.0f, p1=0.0f;
  #pragma unroll
  for (int q=0;q<4;q++){
    int k = tid + q*256;
    float x = fmaf(y2[(size_t)b*DMLP + k], scale2[k], shift2[k]);
    p0 = fmaf(x, W3[k], p0);
    p1 = fmaf(x, W3[DMLP+k], p1);
  }
  r0[tid]=p0; r1[tid]=p1;
  __syncthreads();
  for (int s=128; s>0; s>>=1){
    if (tid<s){ r0[tid]+=r0[tid+s]; r1[tid]+=r1[tid+s]; }
    __syncthreads();
  }
  if (tid==0){
    float l0 = r0[0]+b3[0], l1 = r1[0]+b3[1];
    float m = fmaxf(l0,l1);
    float lse = m + logf(__expf(l0-m)+__expf(l1-m));
    out[b*2+0] = l0-lse;
    out[b*2+1] = l1-lse;
  }
}

// ---------------------------------------------------------------------------
extern "C" void kernel_launch(void* const* d_in, const int* in_sizes, int n_in,
                              void* d_out, int out_size, void* d_ws, size_t ws_size,
                              hipStream_t stream)
{
  (void)in_sizes; (void)n_in; (void)out_size; (void)ws_size;
  const float* embed = (const float*)d_in[0];
  const float* projW = (const float*)d_in[1];
  const float* projb = (const float*)d_in[2];
  const float* bn_g  = (const float*)d_in[3];
  const float* bn_b  = (const float*)d_in[4];
  const float* Wih   = (const float*)d_in[5];
  const float* Whh   = (const float*)d_in[6];
  const float* bih   = (const float*)d_in[7];
  const float* bhh   = (const float*)d_in[8];
  const float* W1    = (const float*)d_in[9];
  const float* b1    = (const float*)d_in[10];
  const float* g1    = (const float*)d_in[11];
  const float* be1   = (const float*)d_in[12];
  const float* W2    = (const float*)d_in[13];
  const float* b2    = (const float*)d_in[14];
  const float* g2    = (const float*)d_in[15];
  const float* be2   = (const float*)d_in[16];
  const float* W3    = (const float*)d_in[17];
  const float* b3    = (const float*)d_in[18];
  const float* extra = (const float*)d_in[19];
  const int*   s1    = (const int*)d_in[20];
  const int*   s2    = (const int*)d_in[21];
  float* out = (float*)d_out;

  float* ws = (float*)d_ws;
  size_t off = 0;
  float* ps   = ws + off; off += (size_t)2*60*EMB;
  float* psq  = ws + off; off += (size_t)2*60*EMB;
  float* bnsc = ws + off; off += 2*EMB;
  float* bnsh = ws + off; off += 2*EMB;
  float* bsum = ws + off; off += 2048;
  unsigned short* Pb     = (unsigned short*)(ws + off); off += (size_t)NROW*EMBP/2;
  unsigned short* Wihb   = (unsigned short*)(ws + off); off += (size_t)2048*EMBP/2;
  unsigned short* Whhb   = (unsigned short*)(ws + off); off += (size_t)2048*HID/2;
  unsigned short* projWb = (unsigned short*)(ws + off); off += (size_t)EMBP*EMBP/2;
  float* cst = ws + off; off += (size_t)512*HID;           // f32 c-state
  unsigned short* Hb0 = (unsigned short*)(ws + off); off += (size_t)512*HID/2;
  unsigned short* Hb1 = (unsigned short*)(ws + off); off += (size_t)512*HID/2;
  unsigned short* Hout = (unsigned short*)(ws + off); off += (size_t)2*S_LEN*BATCH*HID/2;
  float* pooled = ws + off; off += (size_t)BATCH*225;
  float* y1     = ws + off; off += (size_t)BATCH*DMLP;
  float* y2     = ws + off; off += (size_t)BATCH*DMLP;
  float* y2part = ws + off; off += (size_t)4*BATCH*DMLP;
  float* sc1    = ws + off; off += DMLP;
  float* sh1    = ws + off; off += DMLP;
  float* sc2    = ws + off; off += DMLP;
  float* sh2    = ws + off; off += DMLP;
  // total ~18M float-slots ~72 MB

  // zero c-state (f32) + Hb0 (bf16), contiguous
  hipMemsetAsync(cst, 0, (size_t)(512*HID)*sizeof(float) + (size_t)(512*HID)*sizeof(unsigned short), stream);

  k_conv_weights<<<512, 256, 0, stream>>>(Wih, Whh, bih, bhh, projW,
                                          Wihb, Whhb, projWb, bsum);
  k_embed_mfma<<<dim3(NROW/64, 5), 512, 0, stream>>>(embed, projWb, projb, s1, s2, Pb);
  k_bn_partial<<<dim3(60,2), 320, 0, stream>>>(Pb, ps, psq);
  k_bn_final<<<2, 320, 0, stream>>>(ps, psq, bn_g, bn_b, bnsc, bnsh);
  k_bn_apply<<<NROW/8, 256, 0, stream>>>(Pb, bnsc, bnsh);

  for (int t=0; t<S_LEN; t++){
    const unsigned short* hin = (t & 1) ? Hb1 : Hb0;
    unsigned short*      hnxt = (t & 1) ? Hb0 : Hb1;
    k_lstm_step<<<dim3(32,8), 512, 0, stream>>>(Pb, Wihb, Whhb, bsum,
                                                hin, hnxt, cst, Hout, t);
  }

  k_dist_pool<<<BATCH, 256, 0, stream>>>(Hout, pooled);
  k_mlp1_gemm<<<dim3(16,4), 256, 0, stream>>>(pooled, extra, W1, b1, y1);
  k_mlp_bn2<<<16, 256, 0, stream>>>(y1, g1, be1, sc1, sh1);
  k_mlp2_gemm<<<dim3(16,4,4), 256, 0, stream>>>(y1, sc1, sh1, W2, y2part);
  k_mlp2_fin<<<BATCH, 256, 0, stream>>>(y2part, b2, y2);
  k_mlp_bn2<<<16, 256, 0, stream>>>(y2, g2, be2, sc2, sh2);
  k_mlp3<<<BATCH, 256, 0, stream>>>(y2, sc2, sh2, W3, b3, out);
}